// Round 2
// baseline (1113.363 us; speedup 1.0000x reference)
//
#include <hip/hip_runtime.h>
#include <hip/hip_bf16.h>

typedef float f32x2 __attribute__((ext_vector_type(2)));

#define HEADS 8
#define OUT_DIM 8
#define HID 64
#define IN_NODE 128
#define IN_EDGE 64

// ---------------------------------------------------------------------------
// QKV projection: out[node][j] = sum_k h[node][k] * W[k][j] + b[j]
// block = 256 (4 waves); each wave owns a run of nodes; lane = column j.
// W column held per-lane in 128 VGPRs, loaded via volatile (cannot be
// rematerialized -> stays resident). 2 nodes in flight, 2 acc chains each.
// ---------------------------------------------------------------------------
__global__ __launch_bounds__(256, 2) void qkv_kernel(
    const float* __restrict__ h,
    const float* __restrict__ WQ, const float* __restrict__ bQ,
    const float* __restrict__ WK, const float* __restrict__ bK,
    const float* __restrict__ WV, const float* __restrict__ bV,
    float* __restrict__ Q, float* __restrict__ K, float* __restrict__ V,
    int n_nodes, int npw)
{
    const int lane = threadIdx.x & 63;
    const int gw   = blockIdx.x * 4 + (threadIdx.x >> 6);
    const int mat  = blockIdx.y;
    const float* __restrict__ W  = (mat == 0) ? WQ : (mat == 1) ? WK : WV;
    const float* __restrict__ bp = (mat == 0) ? bQ : (mat == 1) ? bK : bV;
    float* __restrict__ out      = (mat == 0) ? Q  : (mat == 1) ? K  : V;

    f32x2 wc2[IN_NODE / 2];
    {
        const volatile float* Wv = W;
#pragma unroll
        for (int t = 0; t < IN_NODE / 2; ++t) {
            float a = Wv[(2 * t) * HID + lane];
            float b = Wv[(2 * t + 1) * HID + lane];
            wc2[t] = f32x2{a, b};
        }
    }
    const float bias = bp[lane];

    int n0 = gw * npw;
    int n1 = n0 + npw; if (n1 > n_nodes) n1 = n_nodes;
    int node = n0;
    for (; node + 2 <= n1; node += 2) {
        const float* hr0 = h + (size_t)node * IN_NODE;
        const float* hr1 = hr0 + IN_NODE;
        f32x2 a0 = {0.f, 0.f}, b0 = {0.f, 0.f};
        f32x2 a1 = {0.f, 0.f}, b1 = {0.f, 0.f};
#pragma unroll
        for (int kk = 0; kk < IN_NODE; kk += 4) {
            float4 v0 = *reinterpret_cast<const float4*>(hr0 + kk);
            float4 v1 = *reinterpret_cast<const float4*>(hr1 + kk);
            a0 = __builtin_elementwise_fma(f32x2{v0.x, v0.y}, wc2[kk / 2], a0);
            b0 = __builtin_elementwise_fma(f32x2{v0.z, v0.w}, wc2[kk / 2 + 1], b0);
            a1 = __builtin_elementwise_fma(f32x2{v1.x, v1.y}, wc2[kk / 2], a1);
            b1 = __builtin_elementwise_fma(f32x2{v1.z, v1.w}, wc2[kk / 2 + 1], b1);
        }
        out[(size_t)node * HID + lane]       = a0.x + a0.y + b0.x + b0.y + bias;
        out[(size_t)(node + 1) * HID + lane] = a1.x + a1.y + b1.x + b1.y + bias;
    }
    for (; node < n1; ++node) {
        const float* hr0 = h + (size_t)node * IN_NODE;
        f32x2 a0 = {0.f, 0.f}, b0 = {0.f, 0.f};
#pragma unroll
        for (int kk = 0; kk < IN_NODE; kk += 4) {
            float4 v0 = *reinterpret_cast<const float4*>(hr0 + kk);
            a0 = __builtin_elementwise_fma(f32x2{v0.x, v0.y}, wc2[kk / 2], a0);
            b0 = __builtin_elementwise_fma(f32x2{v0.z, v0.w}, wc2[kk / 2 + 1], b0);
        }
        out[(size_t)node * HID + lane] = a0.x + a0.y + b0.x + b0.y + bias;
    }
}

// ---------------------------------------------------------------------------
// Edge kernel: block = 256 (4 waves). Each wave owns a run of edges;
// lane = output column j. We column pinned in 64 VGPRs via volatile loads.
// 2 edges in flight, 2 acc chains each (4 independent fma chains).
// K/Q/index gathers hoisted above the fma loop to overlap latency.
// ---------------------------------------------------------------------------
__global__ __launch_bounds__(256, 4) void edge_kernel(
    const int* __restrict__ ei, const float* __restrict__ e,
    const float* __restrict__ We, const float* __restrict__ be,
    const float* __restrict__ Q, const float* __restrict__ K,
    float* __restrict__ e_out, float* __restrict__ z_sum,
    float* __restrict__ cnt, int n_edges, int epw)
{
    const int lane = threadIdx.x & 63;
    const int gw   = blockIdx.x * 4 + (threadIdx.x >> 6);

    f32x2 w2[IN_EDGE / 2];
    {
        const volatile float* Wv = We;
#pragma unroll
        for (int t = 0; t < IN_EDGE / 2; ++t) {
            float a = Wv[(2 * t) * HID + lane];
            float b = Wv[(2 * t + 1) * HID + lane];
            w2[t] = f32x2{a, b};
        }
    }
    const float bias = be[lane];

    int e0 = gw * epw;
    int e1 = e0 + epw; if (e1 > n_edges) e1 = n_edges;
    if (e0 >= e1) return;

    int edge = e0;
    for (; edge + 2 <= e1; edge += 2) {
        // hoist gathers: indices then K/Q rows (coalesced 256B row reads)
        int src0 = ei[edge];
        int dst0 = ei[n_edges + edge];
        int src1 = ei[edge + 1];
        int dst1 = ei[n_edges + edge + 1];
        float k0 = K[(size_t)src0 * HID + lane];
        float q0 = Q[(size_t)dst0 * HID + lane];
        float k1 = K[(size_t)src1 * HID + lane];
        float q1 = Q[(size_t)dst1 * HID + lane];

        const float* er0 = e + (size_t)edge * IN_EDGE;
        const float* er1 = er0 + IN_EDGE;
        f32x2 a0 = {0.f, 0.f}, b0 = {0.f, 0.f};
        f32x2 a1 = {0.f, 0.f}, b1 = {0.f, 0.f};
#pragma unroll
        for (int kk = 0; kk < IN_EDGE; kk += 4) {
            float4 v0 = *reinterpret_cast<const float4*>(er0 + kk);
            float4 v1 = *reinterpret_cast<const float4*>(er1 + kk);
            a0 = __builtin_elementwise_fma(f32x2{v0.x, v0.y}, w2[kk / 2], a0);
            b0 = __builtin_elementwise_fma(f32x2{v0.z, v0.w}, w2[kk / 2 + 1], b0);
            a1 = __builtin_elementwise_fma(f32x2{v1.x, v1.y}, w2[kk / 2], a1);
            b1 = __builtin_elementwise_fma(f32x2{v1.z, v1.w}, w2[kk / 2 + 1], b1);
        }
        float s0 = fmaf(k0 * q0, 0.35355339059327373f, a0.x + a0.y + b0.x + b0.y + bias);
        float s1 = fmaf(k1 * q1, 0.35355339059327373f, a1.x + a1.y + b1.x + b1.y + bias);
        e_out[(size_t)edge * HID + lane]       = s0;
        e_out[(size_t)(edge + 1) * HID + lane] = s1;

        float t0 = s0, t1 = s1;
        t0 += __shfl_xor(t0, 1); t1 += __shfl_xor(t1, 1);
        t0 += __shfl_xor(t0, 2); t1 += __shfl_xor(t1, 2);
        t0 += __shfl_xor(t0, 4); t1 += __shfl_xor(t1, 4);
        if ((lane & 7) == 0) {
            float a0e = __expf(fminf(fmaxf(t0, -5.0f), 5.0f));
            float a1e = __expf(fminf(fmaxf(t1, -5.0f), 5.0f));
            atomicAdd(&z_sum[src0 * HEADS + (lane >> 3)], a0e);
            atomicAdd(&z_sum[src1 * HEADS + (lane >> 3)], a1e);
        }
        if (lane == 0) {
            atomicAdd(&cnt[src0], 1.0f);
            atomicAdd(&cnt[src1], 1.0f);
        }
    }
    for (; edge < e1; ++edge) {
        int src0 = ei[edge];
        int dst0 = ei[n_edges + edge];
        float k0 = K[(size_t)src0 * HID + lane];
        float q0 = Q[(size_t)dst0 * HID + lane];
        const float* er0 = e + (size_t)edge * IN_EDGE;
        f32x2 a0 = {0.f, 0.f}, b0 = {0.f, 0.f};
#pragma unroll
        for (int kk = 0; kk < IN_EDGE; kk += 4) {
            float4 v0 = *reinterpret_cast<const float4*>(er0 + kk);
            a0 = __builtin_elementwise_fma(f32x2{v0.x, v0.y}, w2[kk / 2], a0);
            b0 = __builtin_elementwise_fma(f32x2{v0.z, v0.w}, w2[kk / 2 + 1], b0);
        }
        float s0 = fmaf(k0 * q0, 0.35355339059327373f, a0.x + a0.y + b0.x + b0.y + bias);
        e_out[(size_t)edge * HID + lane] = s0;
        float t0 = s0;
        t0 += __shfl_xor(t0, 1);
        t0 += __shfl_xor(t0, 2);
        t0 += __shfl_xor(t0, 4);
        if ((lane & 7) == 0) {
            float a0e = __expf(fminf(fmaxf(t0, -5.0f), 5.0f));
            atomicAdd(&z_sum[src0 * HEADS + (lane >> 3)], a0e);
        }
        if (lane == 0) atomicAdd(&cnt[src0], 1.0f);
    }
}

// ---------------------------------------------------------------------------
// Finalize: h_out[n,h,d] = V[n,h,d]*S / (S/max(cnt,1) + 1e-6)
// ---------------------------------------------------------------------------
__global__ __launch_bounds__(256) void finalize_kernel(
    const float* __restrict__ V, const float* __restrict__ z_sum,
    const float* __restrict__ cnt, float* __restrict__ h_out, int total)
{
    int i = blockIdx.x * 256 + threadIdx.x;
    if (i >= total) return;
    int node = i >> 6;
    int head = (i >> 3) & 7;
    float S = z_sum[node * HEADS + head];
    float c = fmaxf(cnt[node], 1.0f);
    h_out[i] = V[i] * S / (S / c + 1e-6f);
}

extern "C" void kernel_launch(void* const* d_in, const int* in_sizes, int n_in,
                              void* d_out, int out_size, void* d_ws, size_t ws_size,
                              hipStream_t stream)
{
    const int*   ei = (const int*)d_in[0];
    const float* h  = (const float*)d_in[1];
    const float* e  = (const float*)d_in[2];
    const float* WQ = (const float*)d_in[3];
    const float* bQ = (const float*)d_in[4];
    const float* WK = (const float*)d_in[5];
    const float* bK = (const float*)d_in[6];
    const float* WV = (const float*)d_in[7];
    const float* bV = (const float*)d_in[8];
    const float* We = (const float*)d_in[9];
    const float* be = (const float*)d_in[10];

    const int n_nodes = in_sizes[1] / IN_NODE;   // 50000
    const int n_edges = in_sizes[2] / IN_EDGE;   // 800000

    float* out_h = (float*)d_out;                       // n_nodes*64
    float* out_e = out_h + (size_t)n_nodes * HID;       // n_edges*64

    float* Q     = (float*)d_ws;
    float* K     = Q + (size_t)n_nodes * HID;
    float* V     = K + (size_t)n_nodes * HID;
    float* z_sum = V + (size_t)n_nodes * HID;
    float* cnt   = z_sum + (size_t)n_nodes * HEADS;

    hipMemsetAsync(z_sum, 0, (size_t)n_nodes * (HEADS + 1) * sizeof(float), stream);

    // QKV projection: 256 blocks x 4 waves x 3 mats; npw nodes per wave
    {
        const int nblk = 256;
        const int waves = nblk * 4;
        const int npw = (n_nodes + waves - 1) / waves;
        dim3 grid(nblk, 3);
        qkv_kernel<<<grid, 256, 0, stream>>>(h, WQ, bQ, WK, bK, WV, bV,
                                             Q, K, V, n_nodes, npw);
    }
    // Edge kernel: 2048 blocks x 4 waves; epw edges per wave
    {
        const int nblk = 2048;
        const int waves = nblk * 4;
        const int epw = (n_edges + waves - 1) / waves;
        edge_kernel<<<nblk, 256, 0, stream>>>(ei, e, We, be, Q, K,
                                              out_e, z_sum, cnt, n_edges, epw);
    }
    // Finalize
    {
        const int total = n_nodes * HID;
        finalize_kernel<<<(total + 255) / 256, 256, 0, stream>>>(V, z_sum, cnt,
                                                                 out_h, total);
    }
}

// Round 3
// 279.605 us; speedup vs baseline: 3.9819x; 3.9819x over previous
//
#include <hip/hip_runtime.h>
#include <hip/hip_bf16.h>

typedef float  f32x4  __attribute__((ext_vector_type(4)));
typedef short  bf16x8 __attribute__((ext_vector_type(8)));

#define HEADS 8
#define HID 64
#define IN_NODE 128
#define IN_EDGE 64

// f32 -> bf16 (RNE), as raw bits in a short
static __device__ __forceinline__ short f2bf(float f) {
    unsigned u = __builtin_bit_cast(unsigned, f);
    unsigned r = (u + 0x7FFFu + ((u >> 16) & 1u)) >> 16;
    return (short)r;
}

// ---------------------------------------------------------------------------
// QKV projection via MFMA: out[node][col] = sum_k h[node][k]*W[k][col] + b[col]
// grid.y selects mat (Q/K/V). Each wave: B-frags for its mat's 64 cols
// (4 col-tiles x 4 k-chunks, 64 VGPR), grid-strides over 16-node row tiles.
// Frag maps: A row = lane&15, k-slot = (lane>>4)*8+j ; B col = lane&15, same
// k-slot map (any bijective k map is valid as long as A and B agree).
// C/D (m89-verified): col = lane&15, row = (lane>>4)*4 + reg.
// ---------------------------------------------------------------------------
__global__ __launch_bounds__(256, 4) void qkv_kernel(
    const float* __restrict__ h,
    const float* __restrict__ WQ, const float* __restrict__ bQ,
    const float* __restrict__ WK, const float* __restrict__ bK,
    const float* __restrict__ WV, const float* __restrict__ bV,
    float* __restrict__ Q, float* __restrict__ K, float* __restrict__ V,
    int n_nodes)
{
    const int lane = threadIdx.x & 63;
    const int r16  = lane & 15;
    const int g4   = lane >> 4;
    const int wave   = blockIdx.x * (blockDim.x >> 6) + (threadIdx.x >> 6);
    const int nwaves = gridDim.x * (blockDim.x >> 6);
    const int mat  = blockIdx.y;

    const float* __restrict__ W  = (mat == 0) ? WQ : (mat == 1) ? WK : WV;
    const float* __restrict__ bp = (mat == 0) ? bQ : (mat == 1) ? bK : bV;
    float* __restrict__ out      = (mat == 0) ? Q  : (mat == 1) ? K  : V;

    // B frags: 4 col-tiles x 4 k-chunks
    bf16x8 bfr[4][4];
#pragma unroll
    for (int ct = 0; ct < 4; ++ct)
#pragma unroll
        for (int kc = 0; kc < 4; ++kc)
#pragma unroll
            for (int j = 0; j < 8; ++j) {
                int k = kc * 32 + g4 * 8 + j;
                bfr[ct][kc][j] = f2bf(W[k * HID + ct * 16 + r16]);
            }
    float bias[4];
#pragma unroll
    for (int ct = 0; ct < 4; ++ct) bias[ct] = bp[ct * 16 + r16];

    const int ntiles = (n_nodes + 15) >> 4;
    for (int tile = wave; tile < ntiles; tile += nwaves) {
        const int row0 = tile * 16;
        int arow = row0 + r16; if (arow > n_nodes - 1) arow = n_nodes - 1;
        const float* ap = h + (size_t)arow * IN_NODE + g4 * 8;

        bf16x8 afr[4];
#pragma unroll
        for (int kc = 0; kc < 4; ++kc) {
            float4 p0 = *reinterpret_cast<const float4*>(ap + kc * 32);
            float4 p1 = *reinterpret_cast<const float4*>(ap + kc * 32 + 4);
            afr[kc][0] = f2bf(p0.x); afr[kc][1] = f2bf(p0.y);
            afr[kc][2] = f2bf(p0.z); afr[kc][3] = f2bf(p0.w);
            afr[kc][4] = f2bf(p1.x); afr[kc][5] = f2bf(p1.y);
            afr[kc][6] = f2bf(p1.z); afr[kc][7] = f2bf(p1.w);
        }

        f32x4 acc[4] = {};
#pragma unroll
        for (int ct = 0; ct < 4; ++ct)
#pragma unroll
            for (int kc = 0; kc < 4; ++kc)
                acc[ct] = __builtin_amdgcn_mfma_f32_16x16x32_bf16(
                    afr[kc], bfr[ct][kc], acc[ct], 0, 0, 0);

#pragma unroll
        for (int ct = 0; ct < 4; ++ct)
#pragma unroll
            for (int r = 0; r < 4; ++r) {
                int orow = row0 + g4 * 4 + r;
                if (orow < n_nodes)
                    out[(size_t)orow * HID + ct * 16 + r16] = acc[ct][r] + bias[ct];
            }
    }
}

// ---------------------------------------------------------------------------
// Edge kernel via MFMA: pe = e(16x64) @ We(64x64), then
// score = K[src]*Q[dst]/sqrt(8) + pe + be  -> e_out; per-head sums -> exp ->
// atomic z_sum; cnt[src] += 1.
// Per wave: B-frags (4 ct x 2 kc = 32 VGPR) resident; grid-stride over
// 16-edge tiles.
// ---------------------------------------------------------------------------
__global__ __launch_bounds__(256, 4) void edge_kernel(
    const int* __restrict__ ei, const float* __restrict__ e,
    const float* __restrict__ We, const float* __restrict__ be,
    const float* __restrict__ Q, const float* __restrict__ K,
    float* __restrict__ e_out, float* __restrict__ z_sum,
    float* __restrict__ cnt, int n_edges)
{
    const int lane = threadIdx.x & 63;
    const int r16  = lane & 15;
    const int g4   = lane >> 4;
    const int wave   = blockIdx.x * (blockDim.x >> 6) + (threadIdx.x >> 6);
    const int nwaves = gridDim.x * (blockDim.x >> 6);

    bf16x8 bfr[4][2];
#pragma unroll
    for (int ct = 0; ct < 4; ++ct)
#pragma unroll
        for (int kc = 0; kc < 2; ++kc)
#pragma unroll
            for (int j = 0; j < 8; ++j) {
                int k = kc * 32 + g4 * 8 + j;
                bfr[ct][kc][j] = f2bf(We[k * HID + ct * 16 + r16]);
            }
    float bias[4];
#pragma unroll
    for (int ct = 0; ct < 4; ++ct) bias[ct] = be[ct * 16 + r16];

    const int ntiles = (n_edges + 15) >> 4;
    for (int tile = wave; tile < ntiles; tile += nwaves) {
        const int e0 = tile * 16;
        int arow = e0 + r16; if (arow > n_edges - 1) arow = n_edges - 1;
        const float* ap = e + (size_t)arow * IN_EDGE + g4 * 8;

        bf16x8 afr[2];
#pragma unroll
        for (int kc = 0; kc < 2; ++kc) {
            float4 p0 = *reinterpret_cast<const float4*>(ap + kc * 32);
            float4 p1 = *reinterpret_cast<const float4*>(ap + kc * 32 + 4);
            afr[kc][0] = f2bf(p0.x); afr[kc][1] = f2bf(p0.y);
            afr[kc][2] = f2bf(p0.z); afr[kc][3] = f2bf(p0.w);
            afr[kc][4] = f2bf(p1.x); afr[kc][5] = f2bf(p1.y);
            afr[kc][6] = f2bf(p1.z); afr[kc][7] = f2bf(p1.w);
        }

        f32x4 acc[4] = {};
#pragma unroll
        for (int ct = 0; ct < 4; ++ct) {
            acc[ct] = __builtin_amdgcn_mfma_f32_16x16x32_bf16(afr[0], bfr[ct][0], acc[ct], 0, 0, 0);
            acc[ct] = __builtin_amdgcn_mfma_f32_16x16x32_bf16(afr[1], bfr[ct][1], acc[ct], 0, 0, 0);
        }

        // epilogue: this lane's accs correspond to edge rows g4*4 + r
        int srcs[4], dsts[4];
#pragma unroll
        for (int r = 0; r < 4; ++r) {
            int er = e0 + g4 * 4 + r; if (er > n_edges - 1) er = n_edges - 1;
            srcs[r] = ei[er];
            dsts[r] = ei[n_edges + er];
        }

#pragma unroll
        for (int r = 0; r < 4; ++r) {
            const int erow = e0 + g4 * 4 + r;
            const bool valid = erow < n_edges;
#pragma unroll
            for (int ct = 0; ct < 4; ++ct) {
                const int col = ct * 16 + r16;
                float kv = K[(size_t)srcs[r] * HID + col];
                float qv = Q[(size_t)dsts[r] * HID + col];
                float score = fmaf(kv * qv, 0.35355339059327373f,
                                   acc[ct][r] + bias[ct]);
                if (valid)
                    e_out[(size_t)erow * HID + col] = score;

                float s = score;
                s += __shfl_xor(s, 1);
                s += __shfl_xor(s, 2);
                s += __shfl_xor(s, 4);
                if (valid && (lane & 7) == 0) {
                    float a = __expf(fminf(fmaxf(s, -5.0f), 5.0f));
                    int head = ct * 2 + (r16 >> 3);
                    atomicAdd(&z_sum[srcs[r] * HEADS + head], a);
                }
            }
            if (valid && r16 == 0)
                atomicAdd(&cnt[srcs[r]], 1.0f);
        }
    }
}

// ---------------------------------------------------------------------------
// Finalize: h_out[n,h,d] = V[n,h,d]*S / (S/max(cnt,1) + 1e-6)
// ---------------------------------------------------------------------------
__global__ __launch_bounds__(256) void finalize_kernel(
    const float* __restrict__ V, const float* __restrict__ z_sum,
    const float* __restrict__ cnt, float* __restrict__ h_out, int total)
{
    int i = blockIdx.x * 256 + threadIdx.x;
    if (i >= total) return;
    int node = i >> 6;
    int head = (i >> 3) & 7;
    float S = z_sum[node * HEADS + head];
    float c = fmaxf(cnt[node], 1.0f);
    h_out[i] = V[i] * S / (S / c + 1e-6f);
}

extern "C" void kernel_launch(void* const* d_in, const int* in_sizes, int n_in,
                              void* d_out, int out_size, void* d_ws, size_t ws_size,
                              hipStream_t stream)
{
    const int*   ei = (const int*)d_in[0];
    const float* h  = (const float*)d_in[1];
    const float* e  = (const float*)d_in[2];
    const float* WQ = (const float*)d_in[3];
    const float* bQ = (const float*)d_in[4];
    const float* WK = (const float*)d_in[5];
    const float* bK = (const float*)d_in[6];
    const float* WV = (const float*)d_in[7];
    const float* bV = (const float*)d_in[8];
    const float* We = (const float*)d_in[9];
    const float* be = (const float*)d_in[10];

    const int n_nodes = in_sizes[1] / IN_NODE;   // 50000
    const int n_edges = in_sizes[2] / IN_EDGE;   // 800000

    float* out_h = (float*)d_out;                       // n_nodes*64
    float* out_e = out_h + (size_t)n_nodes * HID;       // n_edges*64

    float* Q     = (float*)d_ws;
    float* K     = Q + (size_t)n_nodes * HID;
    float* V     = K + (size_t)n_nodes * HID;
    float* z_sum = V + (size_t)n_nodes * HID;
    float* cnt   = z_sum + (size_t)n_nodes * HEADS;

    hipMemsetAsync(z_sum, 0, (size_t)n_nodes * (HEADS + 1) * sizeof(float), stream);

    // QKV: 96 blocks x 4 waves x 3 mats, grid-stride over 3125 row tiles
    {
        dim3 grid(96, 3);
        qkv_kernel<<<grid, 256, 0, stream>>>(h, WQ, bQ, WK, bK, WV, bV,
                                             Q, K, V, n_nodes);
    }
    // Edge: 2048 blocks x 4 waves, grid-stride over 50000 edge tiles
    {
        edge_kernel<<<2048, 256, 0, stream>>>(ei, e, We, be, Q, K,
                                              out_e, z_sum, cnt, n_edges);
    }
    // Finalize
    {
        const int total = n_nodes * HID;
        finalize_kernel<<<(total + 255) / 256, 256, 0, stream>>>(V, z_sum, cnt,
                                                                 out_h, total);
    }
}

// Round 5
// 243.727 us; speedup vs baseline: 4.5681x; 1.1472x over previous
//
#include <hip/hip_runtime.h>
#include <hip/hip_bf16.h>

typedef float  f32x4  __attribute__((ext_vector_type(4)));
typedef short  bf16x8 __attribute__((ext_vector_type(8)));

#define HEADS 8
#define HID 64
#define IN_NODE 128
#define IN_EDGE 64
#define LDSP 68   // LDS row pad: 68 words = 272B, 16B-aligned

// f32 -> bf16 (RNE), as raw bits in a short
static __device__ __forceinline__ short f2bf(float f) {
    unsigned u = __builtin_bit_cast(unsigned, f);
    unsigned r = (u + 0x7FFFu + ((u >> 16) & 1u)) >> 16;
    return (short)r;
}

// ---------------------------------------------------------------------------
// QKV projection via MFMA (unchanged from R3 — verified correct).
// ---------------------------------------------------------------------------
__global__ __launch_bounds__(256, 4) void qkv_kernel(
    const float* __restrict__ h,
    const float* __restrict__ WQ, const float* __restrict__ bQ,
    const float* __restrict__ WK, const float* __restrict__ bK,
    const float* __restrict__ WV, const float* __restrict__ bV,
    float* __restrict__ Q, float* __restrict__ K, float* __restrict__ V,
    int n_nodes)
{
    const int lane = threadIdx.x & 63;
    const int r16  = lane & 15;
    const int g4   = lane >> 4;
    const int wave   = blockIdx.x * (blockDim.x >> 6) + (threadIdx.x >> 6);
    const int nwaves = gridDim.x * (blockDim.x >> 6);
    const int mat  = blockIdx.y;

    const float* __restrict__ W  = (mat == 0) ? WQ : (mat == 1) ? WK : WV;
    const float* __restrict__ bp = (mat == 0) ? bQ : (mat == 1) ? bK : bV;
    float* __restrict__ out      = (mat == 0) ? Q  : (mat == 1) ? K  : V;

    bf16x8 bfr[4][4];
#pragma unroll
    for (int ct = 0; ct < 4; ++ct)
#pragma unroll
        for (int kc = 0; kc < 4; ++kc)
#pragma unroll
            for (int j = 0; j < 8; ++j) {
                int k = kc * 32 + g4 * 8 + j;
                bfr[ct][kc][j] = f2bf(W[k * HID + ct * 16 + r16]);
            }
    float bias[4];
#pragma unroll
    for (int ct = 0; ct < 4; ++ct) bias[ct] = bp[ct * 16 + r16];

    const int ntiles = (n_nodes + 15) >> 4;
    for (int tile = wave; tile < ntiles; tile += nwaves) {
        const int row0 = tile * 16;
        int arow = row0 + r16; if (arow > n_nodes - 1) arow = n_nodes - 1;
        const float* ap = h + (size_t)arow * IN_NODE + g4 * 8;

        bf16x8 afr[4];
#pragma unroll
        for (int kc = 0; kc < 4; ++kc) {
            f32x4 p0 = *reinterpret_cast<const f32x4*>(ap + kc * 32);
            f32x4 p1 = *reinterpret_cast<const f32x4*>(ap + kc * 32 + 4);
            afr[kc][0] = f2bf(p0.x); afr[kc][1] = f2bf(p0.y);
            afr[kc][2] = f2bf(p0.z); afr[kc][3] = f2bf(p0.w);
            afr[kc][4] = f2bf(p1.x); afr[kc][5] = f2bf(p1.y);
            afr[kc][6] = f2bf(p1.z); afr[kc][7] = f2bf(p1.w);
        }

        f32x4 acc[4] = {};
#pragma unroll
        for (int ct = 0; ct < 4; ++ct)
#pragma unroll
            for (int kc = 0; kc < 4; ++kc)
                acc[ct] = __builtin_amdgcn_mfma_f32_16x16x32_bf16(
                    afr[kc], bfr[ct][kc], acc[ct], 0, 0, 0);

#pragma unroll
        for (int ct = 0; ct < 4; ++ct)
#pragma unroll
            for (int r = 0; r < 4; ++r) {
                int orow = row0 + g4 * 4 + r;
                if (orow < n_nodes)
                    out[(size_t)orow * HID + ct * 16 + r16] = acc[ct][r] + bias[ct];
            }
    }
}

// ---------------------------------------------------------------------------
// Edge kernel: MFMA for pe = e @ We, then lane-remap epilogue via LDS.
//   MFMA phase: lane = (col r16, k-group g4); acc[ct][r] = pe[row g4*4+r][col]
//   pe (+bias) -> per-wave LDS tile [16][LDSP]
//   Epilogue: lane = (edge el = lane>>2, col-quad qg = lane&3):
//     K/Q as 4+4 dwordx4, pe via 4x ds_read_b128, e_out 4 contiguous
//     nontemporal dwordx4; lane owns heads 2qg,2qg+1 -> in-register sums.
// Intra-wave LDS handoff: same-wave DS ops ordered; s_waitcnt lgkmcnt(0).
// ---------------------------------------------------------------------------
__global__ __launch_bounds__(256, 4) void edge_kernel(
    const int* __restrict__ ei, const float* __restrict__ e,
    const float* __restrict__ We, const float* __restrict__ be,
    const float* __restrict__ Q, const float* __restrict__ K,
    float* __restrict__ e_out, float* __restrict__ z_sum,
    float* __restrict__ cnt, int n_edges)
{
    const int lane = threadIdx.x & 63;
    const int wid  = threadIdx.x >> 6;
    const int r16  = lane & 15;
    const int g4   = lane >> 4;
    const int el   = lane >> 2;   // epilogue: edge-local 0..15
    const int qg   = lane & 3;    // epilogue: col-quad 0..3

    __shared__ float plds[4][16][LDSP];
    float (*my)[LDSP] = plds[wid];

    const int wave   = blockIdx.x * 4 + wid;
    const int nwaves = gridDim.x * 4;

    bf16x8 bfr[4][2];
#pragma unroll
    for (int ct = 0; ct < 4; ++ct)
#pragma unroll
        for (int kc = 0; kc < 2; ++kc)
#pragma unroll
            for (int j = 0; j < 8; ++j) {
                int k = kc * 32 + g4 * 8 + j;
                bfr[ct][kc][j] = f2bf(We[k * HID + ct * 16 + r16]);
            }
    float bias[4];
#pragma unroll
    for (int ct = 0; ct < 4; ++ct) bias[ct] = be[ct * 16 + r16];

    const float SC = 0.35355339059327373f;
    const int ntiles = (n_edges + 15) >> 4;
    for (int tile = wave; tile < ntiles; tile += nwaves) {
        const int e0 = tile * 16;

        // ---- A-frag: 16 e-rows, f32 -> bf16 (nontemporal: streamed once)
        int arow = e0 + r16; if (arow > n_edges - 1) arow = n_edges - 1;
        const float* ap = e + (size_t)arow * IN_EDGE + g4 * 8;
        f32x4 p0a = __builtin_nontemporal_load(reinterpret_cast<const f32x4*>(ap));
        f32x4 p1a = __builtin_nontemporal_load(reinterpret_cast<const f32x4*>(ap + 4));
        f32x4 p0b = __builtin_nontemporal_load(reinterpret_cast<const f32x4*>(ap + 32));
        f32x4 p1b = __builtin_nontemporal_load(reinterpret_cast<const f32x4*>(ap + 36));

        bf16x8 afr[2];
        afr[0][0] = f2bf(p0a.x); afr[0][1] = f2bf(p0a.y);
        afr[0][2] = f2bf(p0a.z); afr[0][3] = f2bf(p0a.w);
        afr[0][4] = f2bf(p1a.x); afr[0][5] = f2bf(p1a.y);
        afr[0][6] = f2bf(p1a.z); afr[0][7] = f2bf(p1a.w);
        afr[1][0] = f2bf(p0b.x); afr[1][1] = f2bf(p0b.y);
        afr[1][2] = f2bf(p0b.z); afr[1][3] = f2bf(p0b.w);
        afr[1][4] = f2bf(p1b.x); afr[1][5] = f2bf(p1b.y);
        afr[1][6] = f2bf(p1b.z); afr[1][7] = f2bf(p1b.w);

        f32x4 acc[4] = {};
#pragma unroll
        for (int ct = 0; ct < 4; ++ct) {
            acc[ct] = __builtin_amdgcn_mfma_f32_16x16x32_bf16(afr[0], bfr[ct][0], acc[ct], 0, 0, 0);
            acc[ct] = __builtin_amdgcn_mfma_f32_16x16x32_bf16(afr[1], bfr[ct][1], acc[ct], 0, 0, 0);
        }

        // ---- pe + bias -> LDS
#pragma unroll
        for (int ct = 0; ct < 4; ++ct)
#pragma unroll
            for (int r = 0; r < 4; ++r)
                my[g4 * 4 + r][ct * 16 + r16] = acc[ct][r] + bias[ct];

        // ---- epilogue lane remap: (el, qg)
        int erow = e0 + el;
        bool valid = erow < n_edges;
        int erc = valid ? erow : n_edges - 1;
        int src = ei[erc];
        int dst = ei[n_edges + erc];

        const float* Kp = K + (size_t)src * HID + qg * 16;
        const float* Qp = Q + (size_t)dst * HID + qg * 16;
        f32x4 k0 = *reinterpret_cast<const f32x4*>(Kp);
        f32x4 k1 = *reinterpret_cast<const f32x4*>(Kp + 4);
        f32x4 k2 = *reinterpret_cast<const f32x4*>(Kp + 8);
        f32x4 k3 = *reinterpret_cast<const f32x4*>(Kp + 12);
        f32x4 q0 = *reinterpret_cast<const f32x4*>(Qp);
        f32x4 q1 = *reinterpret_cast<const f32x4*>(Qp + 4);
        f32x4 q2 = *reinterpret_cast<const f32x4*>(Qp + 8);
        f32x4 q3 = *reinterpret_cast<const f32x4*>(Qp + 12);

        // LDS handoff: same-wave DS ordering + explicit wait
        asm volatile("s_waitcnt lgkmcnt(0)" ::: "memory");
        const float* mrow = &my[el][qg * 16];
        f32x4 p0 = *reinterpret_cast<const f32x4*>(mrow);
        f32x4 p1 = *reinterpret_cast<const f32x4*>(mrow + 4);
        f32x4 p2 = *reinterpret_cast<const f32x4*>(mrow + 8);
        f32x4 p3 = *reinterpret_cast<const f32x4*>(mrow + 12);

        f32x4 s0 = k0 * q0 * SC + p0;
        f32x4 s1 = k1 * q1 * SC + p1;
        f32x4 s2 = k2 * q2 * SC + p2;
        f32x4 s3 = k3 * q3 * SC + p3;

        if (valid) {
            float* op = e_out + (size_t)erow * HID + qg * 16;
            __builtin_nontemporal_store(s0, reinterpret_cast<f32x4*>(op));
            __builtin_nontemporal_store(s1, reinterpret_cast<f32x4*>(op + 4));
            __builtin_nontemporal_store(s2, reinterpret_cast<f32x4*>(op + 8));
            __builtin_nontemporal_store(s3, reinterpret_cast<f32x4*>(op + 12));
        }

        // lane owns heads 2qg and 2qg+1 fully: in-register reductions
        float hs0 = ((s0.x + s0.y) + (s0.z + s0.w)) + ((s1.x + s1.y) + (s1.z + s1.w));
        float hs1 = ((s2.x + s2.y) + (s2.z + s2.w)) + ((s3.x + s3.y) + (s3.z + s3.w));
        float a0 = __expf(fminf(fmaxf(hs0, -5.0f), 5.0f));
        float a1 = __expf(fminf(fmaxf(hs1, -5.0f), 5.0f));
        if (valid) {
            atomicAdd(&z_sum[src * HEADS + qg * 2], a0);
            atomicAdd(&z_sum[src * HEADS + qg * 2 + 1], a1);
            if (qg == 0) atomicAdd(&cnt[src], 1.0f);
        }
    }
}

// ---------------------------------------------------------------------------
// Finalize: h_out[n,h,d] = V[n,h,d]*S / (S/max(cnt,1) + 1e-6)
// ---------------------------------------------------------------------------
__global__ __launch_bounds__(256) void finalize_kernel(
    const float* __restrict__ V, const float* __restrict__ z_sum,
    const float* __restrict__ cnt, float* __restrict__ h_out, int total)
{
    int i = blockIdx.x * 256 + threadIdx.x;
    if (i >= total) return;
    int node = i >> 6;
    int head = (i >> 3) & 7;
    float S = z_sum[node * HEADS + head];
    float c = fmaxf(cnt[node], 1.0f);
    h_out[i] = V[i] * S / (S / c + 1e-6f);
}

extern "C" void kernel_launch(void* const* d_in, const int* in_sizes, int n_in,
                              void* d_out, int out_size, void* d_ws, size_t ws_size,
                              hipStream_t stream)
{
    const int*   ei = (const int*)d_in[0];
    const float* h  = (const float*)d_in[1];
    const float* e  = (const float*)d_in[2];
    const float* WQ = (const float*)d_in[3];
    const float* bQ = (const float*)d_in[4];
    const float* WK = (const float*)d_in[5];
    const float* bK = (const float*)d_in[6];
    const float* WV = (const float*)d_in[7];
    const float* bV = (const float*)d_in[8];
    const float* We = (const float*)d_in[9];
    const float* be = (const float*)d_in[10];

    const int n_nodes = in_sizes[1] / IN_NODE;   // 50000
    const int n_edges = in_sizes[2] / IN_EDGE;   // 800000

    float* out_h = (float*)d_out;                       // n_nodes*64
    float* out_e = out_h + (size_t)n_nodes * HID;       // n_edges*64

    float* Q     = (float*)d_ws;
    float* K     = Q + (size_t)n_nodes * HID;
    float* V     = K + (size_t)n_nodes * HID;
    float* z_sum = V + (size_t)n_nodes * HID;
    float* cnt   = z_sum + (size_t)n_nodes * HEADS;

    (void)hipMemsetAsync(z_sum, 0, (size_t)n_nodes * (HEADS + 1) * sizeof(float), stream);

    // QKV: 96 blocks x 4 waves x 3 mats, grid-stride over 3125 row tiles
    {
        dim3 grid(96, 3);
        qkv_kernel<<<grid, 256, 0, stream>>>(h, WQ, bQ, WK, bK, WV, bV,
                                             Q, K, V, n_nodes);
    }
    // Edge: 2048 blocks x 4 waves, grid-stride over 50000 edge tiles
    {
        edge_kernel<<<2048, 256, 0, stream>>>(ei, e, We, be, Q, K,
                                              out_e, z_sum, cnt, n_edges);
    }
    // Finalize
    {
        const int total = n_nodes * HID;
        finalize_kernel<<<(total + 255) / 256, 256, 0, stream>>>(V, z_sum, cnt,
                                                                 out_h, total);
    }
}